// Round 1
// baseline (424.148 us; speedup 1.0000x reference)
//
#include <hip/hip_runtime.h>

typedef __attribute__((ext_vector_type(4)))  float f32x4;
typedef __attribute__((ext_vector_type(16))) float f32x16;
typedef __attribute__((ext_vector_type(8)))  short s16x8;
typedef __attribute__((ext_vector_type(4)))  short s16x4;

// B=512, T=256, E=384, H=64.

__device__ inline short f2bf(float f){
  unsigned u = __float_as_uint(f);
  u = u + 0x7fffu + ((u >> 16) & 1u);   // round-to-nearest-even
  return (short)(u >> 16);
}

__device__ __forceinline__ void gld16(const void* g, void* l){
  __builtin_amdgcn_global_load_lds((const __attribute__((address_space(1))) void*)g,
                                   (__attribute__((address_space(3))) void*)l, 16, 0, 0);
}

// ---------------- Kernel 0: Wt[n][k] = W_{n/64}[k][n%64]  (bf16) ----------------
__global__ void wt_prep_kernel(const float* __restrict__ Wq, const float* __restrict__ Wk,
                               const float* __restrict__ Wv, short* __restrict__ Wt){
  int o = blockIdx.x * 256 + threadIdx.x;
  if (o >= 192*384) return;
  int n = o / 384, k = o - n*384;
  const float* W = (n < 64) ? Wq : (n < 128) ? Wk : Wv;
  Wt[o] = f2bf(W[k*64 + (n & 63)]);
}

// ---------------- Kernel A: QKV projection (no LDS, 2 blocks/CU) ----------------
// 1 block = 1 batch, 8 waves, 2 passes of 16 rows each. 16x16x32 MFMA.
// Writes bf16 Q [b][t][h] row-major; K as the swizzled LDS image
// (byte-in-row ^ (t&7)<<4); V transposed [b][h][t] swizzled (^ (h&7)<<4),
// obtained by swapping MFMA operands so the accumulator is already h-major.
__global__ __launch_bounds__(512, 4) void qkv_kernel(const float* __restrict__ x,
    const short* __restrict__ Wt, short* __restrict__ Qg,
    short* __restrict__ Kg, short* __restrict__ Vg){
  const int tid  = threadIdx.x;
  const int w    = tid >> 6, lane = tid & 63;
  const int l15  = lane & 15, quad = lane >> 4;
  const int b    = blockIdx.x;

  const float* xb = x + (long)b*256*384;
  short* Qb = Qg + (long)b*16384;
  char*  Kb = (char*)(Kg + (long)b*16384);
  char*  Vb = (char*)(Vg + (long)b*16384);

  #pragma unroll 1
  for (int p = 0; p < 2; ++p){
    const int r0 = w*32 + p*16;
    const int tr = r0 + l15;                       // this lane's x row / Q,K out row

    f32x4 aq[4], ak[4], av[4];
    #pragma unroll
    for (int c = 0; c < 4; ++c)
      #pragma unroll
      for (int i = 0; i < 4; ++i){ aq[c][i]=0.f; ak[c][i]=0.f; av[c][i]=0.f; }

    const float* xr = xb + (long)tr*384;
    #pragma unroll 2
    for (int kt = 0; kt < 12; ++kt){
      const int k0 = kt*32 + quad*8;
      float4 a0 = *(const float4*)(xr + k0);
      float4 a1 = *(const float4*)(xr + k0 + 4);
      s16x8 bx;                                    // lane=row, k=quad*8+j (A- and B-compatible)
      bx[0]=f2bf(a0.x); bx[1]=f2bf(a0.y); bx[2]=f2bf(a0.z); bx[3]=f2bf(a0.w);
      bx[4]=f2bf(a1.x); bx[5]=f2bf(a1.y); bx[6]=f2bf(a1.z); bx[7]=f2bf(a1.w);
      #pragma unroll
      for (int c = 0; c < 4; ++c){                 // Q: A=W (m=outcol), B=x (n=row)
        s16x8 wq = *(const s16x8*)(Wt + (c*16 + l15)*384 + k0);
        aq[c] = __builtin_amdgcn_mfma_f32_16x16x32_bf16(wq, bx, aq[c], 0, 0, 0);
      }
      #pragma unroll
      for (int c = 0; c < 4; ++c){                 // K
        s16x8 wk = *(const s16x8*)(Wt + ((c+4)*16 + l15)*384 + k0);
        ak[c] = __builtin_amdgcn_mfma_f32_16x16x32_bf16(wk, bx, ak[c], 0, 0, 0);
      }
      #pragma unroll
      for (int c = 0; c < 4; ++c){                 // V swapped: A=x (m=row), B=W (n=h)
        s16x8 wv = *(const s16x8*)(Wt + ((c+8)*16 + l15)*384 + k0);
        av[c] = __builtin_amdgcn_mfma_f32_16x16x32_bf16(bx, wv, av[c], 0, 0, 0);
      }
    }

    // Q epilogue: D col(l15)=row, row(m)=quad*4+i = outcol-local -> h=c*16+quad*4+i
    #pragma unroll
    for (int c = 0; c < 4; ++c){
      s16x4 v;
      #pragma unroll
      for (int i = 0; i < 4; ++i) v[i] = f2bf(aq[c][i]);
      *(s16x4*)(Qb + tr*64 + c*16 + quad*4) = v;
    }
    // K epilogue: swizzled row-major image (row=tr, 128 B/row)
    {
      const int swz = (tr & 7) << 4;
      #pragma unroll
      for (int c = 0; c < 4; ++c){
        s16x4 v;
        #pragma unroll
        for (int i = 0; i < 4; ++i) v[i] = f2bf(ak[c][i]);
        *(s16x4*)(Kb + tr*128 + ((c*32 + quad*8) ^ swz)) = v;
      }
    }
    // V epilogue: lane holds h=c*16+l15; regs are t=r0+quad*4+i (consecutive) -> [h][t]
    #pragma unroll
    for (int c = 0; c < 4; ++c){
      const int h   = c*16 + l15;
      const int swz = (h & 7) << 4;
      s16x4 v;
      #pragma unroll
      for (int i = 0; i < 4; ++i) v[i] = f2bf(av[c][i]);
      *(s16x4*)(Vb + h*512 + (((r0 + quad*4)*2) ^ swz)) = v;
    }
  }
}

// ---------------- Kernel B: causal attention (LDS 75776 B -> 2 blocks/CU) ----------------
// 1 block = 1 batch, 8 waves. K/V staged linearly via global_load_lds (swizzle
// pre-baked in global). Q loaded straight to registers. Wave w owns q-frags
// {w, 15-w} (balanced causal work: 17 key-frags each).
__global__ __launch_bounds__(512, 4) void attn_kernel(const short* __restrict__ Qg,
    const short* __restrict__ Kg, const short* __restrict__ Vg,
    float* __restrict__ out){
  __shared__ __align__(16) short Ks[16384];     // 32768 B swizzled [t][h] image
  __shared__ __align__(16) short Vts[16384];    // 32768 B swizzled [h][t] image
  __shared__ __align__(16) short Pp[8][16*40];  // 10240 B per-wave P scratch

  const int tid  = threadIdx.x;
  const int w    = tid >> 6, lane = tid & 63;
  const int l15  = lane & 15, quad = lane >> 4;
  const int b    = blockIdx.x;

  // Q prefetch for both frags (issued before staging; independent of LDS)
  const short* Qb = Qg + (long)b*16384;
  const int F0 = w, F1 = 15 - w;
  s16x8 qA0 = *(const s16x8*)(Qb + (F0*16 + l15)*64 + quad*8);
  s16x8 qA1 = *(const s16x8*)(Qb + (F0*16 + l15)*64 + 32 + quad*8);
  s16x8 qB0 = *(const s16x8*)(Qb + (F1*16 + l15)*64 + quad*8);
  s16x8 qB1 = *(const s16x8*)(Qb + (F1*16 + l15)*64 + 32 + quad*8);

  // Stage K,V: 32768 B each, 8 waves x 4 insts x 1024 B
  const char* Kb = (const char*)(Kg + (long)b*16384);
  const char* Vb = (const char*)(Vg + (long)b*16384);
  {
    const int base = w*4096;
    #pragma unroll
    for (int i = 0; i < 4; ++i){
      gld16(Kb + base + i*1024 + lane*16, (char*)Ks  + base + i*1024);
      gld16(Vb + base + i*1024 + lane*16, (char*)Vts + base + i*1024);
    }
  }
  __syncthreads();

  float* ob = out + (long)b*256*64;
  short* Pw = Pp[w];
  const int swz = (l15 & 7) << 4;

  auto attend = [&](int F, s16x8 qf0, s16x8 qf1){
    const int qb = F*16;
    const int NF = F + 1;                         // causal key-frags needed (1..16)
    const int NS = (NF + 1) >> 1;                 // 32-key PV steps

    f32x4 sc[16];
    #pragma unroll
    for (int f = 0; f < 16; ++f){
      f32x4 a;
      #pragma unroll
      for (int r = 0; r < 4; ++r) a[r] = 0.0f;
      if (f < NF){
        const char* kp = (const char*)Ks + (f*16 + l15)*128;
        s16x8 k0v = *(const s16x8*)(kp + ((quad*16)      ^ swz));
        s16x8 k1v = *(const s16x8*)(kp + ((64 + quad*16) ^ swz));
        a = __builtin_amdgcn_mfma_f32_16x16x32_bf16(qf0, k0v, a, 0, 0, 0);
        a = __builtin_amdgcn_mfma_f32_16x16x32_bf16(qf1, k1v, a, 0, 0, 0);
      }
      sc[f] = a;
    }

    // softmax: C col=key=f*16+l15, row=q=quad*4+r
    float mx[4], sm[4];
    #pragma unroll
    for (int r = 0; r < 4; ++r) mx[r] = -3.0e38f;
    #pragma unroll
    for (int f = 0; f < 16; ++f){
      if (f < NF){
        const int key = f*16 + l15;
        #pragma unroll
        for (int r = 0; r < 4; ++r){
          const int qg = qb + quad*4 + r;
          float s = sc[f][r] * 0.125f;            // d^-0.5, H=64
          s = (key <= qg) ? s : -1.0e30f;
          sc[f][r] = s;
          mx[r] = fmaxf(mx[r], s);
        }
      }
    }
    #pragma unroll
    for (int r = 0; r < 4; ++r){
      #pragma unroll
      for (int off = 1; off < 16; off <<= 1) mx[r] = fmaxf(mx[r], __shfl_xor(mx[r], off, 16));
    }
    #pragma unroll
    for (int r = 0; r < 4; ++r) sm[r] = 0.0f;
    #pragma unroll
    for (int f = 0; f < 16; ++f){
      if (f < NF){
        #pragma unroll
        for (int r = 0; r < 4; ++r){
          float p = exp2f((sc[f][r] - mx[r]) * 1.44269504f);
          sc[f][r] = p;
          sm[r] += p;
        }
      }
    }
    #pragma unroll
    for (int r = 0; r < 4; ++r){
      #pragma unroll
      for (int off = 1; off < 16; off <<= 1) sm[r] += __shfl_xor(sm[r], off, 16);
    }

    // PV: A = P (LDS round-trip C->A layout), B = Vts rows (swizzled)
    f32x4 o[4];
    #pragma unroll
    for (int h0 = 0; h0 < 4; ++h0)
      #pragma unroll
      for (int r = 0; r < 4; ++r) o[h0][r] = 0.0f;

    #pragma unroll
    for (int ks = 0; ks < 8; ++ks){
      if (ks < NS){
        #pragma unroll
        for (int fi = 0; fi < 2; ++fi){
          const int f = 2*ks + fi;
          #pragma unroll
          for (int r = 0; r < 4; ++r){
            short v = 0;
            if (f < NF) v = f2bf(sc[f][r]);
            Pw[(quad*4 + r)*40 + fi*16 + l15] = v;
          }
        }
        s16x8 pf = *(const s16x8*)(Pw + l15*40 + quad*8);   // A[m=q][k]
        #pragma unroll
        for (int h0 = 0; h0 < 4; ++h0){
          const char* vp = (const char*)Vts + (h0*16 + l15)*512;
          s16x8 vf = *(const s16x8*)(vp + ((ks*64 + quad*16) ^ swz));
          o[h0] = __builtin_amdgcn_mfma_f32_16x16x32_bf16(pf, vf, o[h0], 0, 0, 0);
        }
      }
    }

    #pragma unroll
    for (int r = 0; r < 4; ++r){
      const float inv = 1.0f / sm[r];
      #pragma unroll
      for (int h0 = 0; h0 < 4; ++h0)
        ob[(qb + quad*4 + r)*64 + h0*16 + l15] = o[h0][r] * inv;
    }
  };
  attend(F0, qA0, qA1);
  attend(F1, qB0, qB1);
}

// ---------------- Fallback: previous fused kernel (used if ws too small) ----------------
__global__ __launch_bounds__(512, 2) void fused_kernel(const float* __restrict__ x,
                             const short* __restrict__ Wt, float* __restrict__ out){
  __shared__ __align__(16) short Qs[256*72];
  __shared__ __align__(16) short Ks2[256*72];
  __shared__ __align__(16) short Vts2[64*264];
  __shared__ __align__(16) short Pp2[8][16*40];

  const int tid  = threadIdx.x;
  const int w    = tid >> 6, lane = tid & 63;
  const int l31  = lane & 31, hh = lane >> 5;
  const int b    = blockIdx.x;

  const float* xb = x + ((long)b*256 + w*32)*384;

  f32x16 acc[6];
  #pragma unroll
  for (int c = 0; c < 6; ++c)
    #pragma unroll
    for (int j = 0; j < 16; ++j) acc[c][j] = 0.0f;

  #pragma unroll 2
  for (int kt = 0; kt < 6; ++kt){
    #pragma unroll
    for (int s = 0; s < 4; ++s){
      const int k0 = kt*64 + s*16 + hh*8;
      const float* xp = xb + l31*384 + k0;
      float4 a0 = *(const float4*)xp;
      float4 a1 = *(const float4*)(xp + 4);
      s16x8 bx;
      bx[0]=f2bf(a0.x); bx[1]=f2bf(a0.y); bx[2]=f2bf(a0.z); bx[3]=f2bf(a0.w);
      bx[4]=f2bf(a1.x); bx[5]=f2bf(a1.y); bx[6]=f2bf(a1.z); bx[7]=f2bf(a1.w);
      #pragma unroll
      for (int c = 0; c < 6; ++c){
        s16x8 wa = *(const s16x8*)(Wt + (c*32 + l31)*384 + k0);
        acc[c] = __builtin_amdgcn_mfma_f32_32x32x16_bf16(wa, bx, acc[c], 0, 0, 0);
      }
    }
  }

  const int trow = w*32 + l31;
  #pragma unroll
  for (int c = 0; c < 4; ++c){
    short* dst = (c < 2) ? Qs : Ks2;
    const int nb = (c & 1)*32;
    #pragma unroll
    for (int g = 0; g < 4; ++g){
      s16x4 v;
      #pragma unroll
      for (int i = 0; i < 4; ++i) v[i] = f2bf(acc[c][g*4 + i]);
      *(s16x4*)(dst + trow*72 + nb + 8*g + 4*hh) = v;
    }
  }
  #pragma unroll
  for (int c = 4; c < 6; ++c)
    #pragma unroll
    for (int reg = 0; reg < 16; ++reg){
      const int h = (c-4)*32 + (reg & 3) + 8*(reg >> 2) + 4*hh;
      Vts2[h*264 + trow] = f2bf(acc[c][reg]);
    }

  __syncthreads();

  const int l15 = lane & 15, quad = lane >> 4;
  float* ob = out + (long)b*256*64;
  short* Pw = Pp2[w];

  for (int it = 0; it < 2; ++it){
    const int F  = it ? (15 - w) : w;
    const int qb = F*16;
    const int NF = F + 1;
    const int NS = (NF + 1) >> 1;

    s16x8 qf0 = *(const s16x8*)(Qs + (qb + l15)*72 + quad*8);
    s16x8 qf1 = *(const s16x8*)(Qs + (qb + l15)*72 + 32 + quad*8);

    f32x4 sc[16];
    #pragma unroll
    for (int f = 0; f < 16; ++f){
      f32x4 a;
      #pragma unroll
      for (int r = 0; r < 4; ++r) a[r] = 0.0f;
      if (f < NF){
        const short* kp = Ks2 + (f*16 + l15)*72 + quad*8;
        s16x8 k0v = *(const s16x8*)kp;
        s16x8 k1v = *(const s16x8*)(kp + 32);
        a = __builtin_amdgcn_mfma_f32_16x16x32_bf16(qf0, k0v, a, 0, 0, 0);
        a = __builtin_amdgcn_mfma_f32_16x16x32_bf16(qf1, k1v, a, 0, 0, 0);
      }
      sc[f] = a;
    }

    float mx[4], sm[4];
    #pragma unroll
    for (int r = 0; r < 4; ++r) mx[r] = -3.0e38f;
    #pragma unroll
    for (int f = 0; f < 16; ++f){
      if (f < NF){
        const int key = f*16 + l15;
        #pragma unroll
        for (int r = 0; r < 4; ++r){
          const int qg = qb + quad*4 + r;
          float s = sc[f][r] * 0.125f;
          s = (key <= qg) ? s : -1.0e30f;
          sc[f][r] = s;
          mx[r] = fmaxf(mx[r], s);
        }
      }
    }
    #pragma unroll
    for (int r = 0; r < 4; ++r){
      #pragma unroll
      for (int off = 1; off < 16; off <<= 1) mx[r] = fmaxf(mx[r], __shfl_xor(mx[r], off, 16));
    }
    #pragma unroll
    for (int r = 0; r < 4; ++r) sm[r] = 0.0f;
    #pragma unroll
    for (int f = 0; f < 16; ++f){
      if (f < NF){
        #pragma unroll
        for (int r = 0; r < 4; ++r){
          float p = exp2f((sc[f][r] - mx[r]) * 1.44269504f);
          sc[f][r] = p;
          sm[r] += p;
        }
      }
    }
    #pragma unroll
    for (int r = 0; r < 4; ++r){
      #pragma unroll
      for (int off = 1; off < 16; off <<= 1) sm[r] += __shfl_xor(sm[r], off, 16);
    }

    f32x4 o[4];
    #pragma unroll
    for (int h0 = 0; h0 < 4; ++h0)
      #pragma unroll
      for (int r = 0; r < 4; ++r) o[h0][r] = 0.0f;

    #pragma unroll
    for (int ks = 0; ks < 8; ++ks){
      if (ks < NS){
        #pragma unroll
        for (int fi = 0; fi < 2; ++fi){
          const int f = 2*ks + fi;
          #pragma unroll
          for (int r = 0; r < 4; ++r){
            short v = 0;
            if (f < NF) v = f2bf(sc[f][r]);
            Pw[(quad*4 + r)*40 + fi*16 + l15] = v;
          }
        }
        s16x8 pf = *(const s16x8*)(Pw + l15*40 + quad*8);
        #pragma unroll
        for (int h0 = 0; h0 < 4; ++h0){
          s16x8 vf = *(const s16x8*)(Vts2 + (h0*16 + l15)*264 + ks*32 + quad*8);
          o[h0] = __builtin_amdgcn_mfma_f32_16x16x32_bf16(pf, vf, o[h0], 0, 0, 0);
        }
      }
    }

    #pragma unroll
    for (int r = 0; r < 4; ++r){
      const float inv = 1.0f / sm[r];
      #pragma unroll
      for (int h0 = 0; h0 < 4; ++h0)
        ob[(qb + quad*4 + r)*64 + h0*16 + l15] = o[h0][r] * inv;
    }
  }
}

extern "C" void kernel_launch(void* const* d_in, const int* in_sizes, int n_in,
                              void* d_out, int out_size, void* d_ws, size_t ws_size,
                              hipStream_t stream){
  const float* x  = (const float*)d_in[0];
  const float* Wq = (const float*)d_in[1];
  const float* Wk = (const float*)d_in[2];
  const float* Wv = (const float*)d_in[3];
  float* out = (float*)d_out;

  short* Wt = (short*)d_ws;                        // 192*384*2 = 147456 B
  const size_t need = 147456 + 3ull*16777216ull;   // Wt + Q/K/V bf16 images

  hipLaunchKernelGGL(wt_prep_kernel, dim3(288), dim3(256), 0, stream, Wq, Wk, Wv, Wt);
  if (ws_size >= need){
    short* Qg = (short*)((char*)d_ws + 147456);
    short* Kg = Qg + 8388608;
    short* Vg = Kg + 8388608;
    hipLaunchKernelGGL(qkv_kernel,  dim3(512), dim3(512), 0, stream, x, Wt, Qg, Kg, Vg);
    hipLaunchKernelGGL(attn_kernel, dim3(512), dim3(512), 0, stream, Qg, Kg, Vg, out);
  } else {
    hipLaunchKernelGGL(fused_kernel, dim3(512), dim3(512), 0, stream, x, Wt, out);
  }
}

// Round 2
// 396.067 us; speedup vs baseline: 1.0709x; 1.0709x over previous
//
#include <hip/hip_runtime.h>

typedef __attribute__((ext_vector_type(4)))  float f32x4;
typedef __attribute__((ext_vector_type(8)))  short s16x8;
typedef __attribute__((ext_vector_type(4)))  short s16x4;

// B=512, T=256, E=384, H=64.

__device__ inline short f2bf(float f){
  unsigned u = __float_as_uint(f);
  u = u + 0x7fffu + ((u >> 16) & 1u);   // round-to-nearest-even
  return (short)(u >> 16);
}

// ---------------- Kernel 0: Wt[n][k] = W_{n/64}[k][n%64]  (bf16) ----------------
// rows 0..63 = Wq cols, 64..127 = Wk cols, 128..191 = Wv cols.
__global__ void wt_prep_kernel(const float* __restrict__ Wq, const float* __restrict__ Wk,
                               const float* __restrict__ Wv, short* __restrict__ Wt){
  int o = blockIdx.x * 256 + threadIdx.x;
  if (o >= 192*384) return;
  int n = o / 384, k = o - n*384;
  const float* W = (n < 64) ? Wq : (n < 128) ? Wk : Wv;
  Wt[o] = f2bf(W[k*64 + (n & 63)]);
}

// ---------------- Fused QKV-projection + causal attention, v2 ----------------
// 1 block = 1 batch, 8 waves, LDS = 75776 B -> 2 blocks/CU (vs 1 before).
// Phase 1: wave w projects the rows of ITS OWN phase-2 q-frags: pass 0 = rows
// [16w,16w+16) (frag w), pass 1 = rows [16(15-w),16(16-w)) (frag 15-w).
// Q never crosses waves: accumulator -> 2KB wave-private LDS bounce (through
// the wave's own K-image rows, before K is written) -> A-frag registers.
// K image: swizzled row-major [t][h], 128 B rows, byte ^ ((t&7)<<4).
// V image: swizzled [h][t], 512 B rows, byte ^ ((h&7)<<4) (operand-swapped
// MFMA so the accumulator is already h-major).  Both layouts harness-verified
// in the round-1 split kernels.
// Phase 2: identical in-LDS attention as the verified kernel.
__global__ __launch_bounds__(512, 4) void fused2_kernel(const float* __restrict__ x,
                             const short* __restrict__ Wt, float* __restrict__ out){
  __shared__ __align__(16) char  KsB[32768];    // [256][128B] swizzled K image
  __shared__ __align__(16) char  VtsB[32768];   // [64][512B]  swizzled V^T image
  __shared__ __align__(16) short Pp[8][16*40];  // 10240 B per-wave P scratch

  const int tid  = threadIdx.x;
  const int w    = tid >> 6, lane = tid & 63;
  const int l15  = lane & 15, quad = lane >> 4;
  const int b    = blockIdx.x;

  const float* xb = x + (long)b*256*384;
  const int F0 = w, F1 = 15 - w;

  s16x8 qA0, qA1, qB0, qB1;

  // ================= Phase 1: project rows of one q-frag =================
  auto project = [&](int r0, s16x8& qf0, s16x8& qf1){
    f32x4 aq[4], ak[4], av[4];
    #pragma unroll
    for (int c = 0; c < 4; ++c)
      #pragma unroll
      for (int i = 0; i < 4; ++i){ aq[c][i]=0.f; ak[c][i]=0.f; av[c][i]=0.f; }

    const float* xr = xb + (long)(r0 + l15)*384;
    #pragma unroll 2
    for (int kt = 0; kt < 12; ++kt){
      const int k0 = kt*32 + quad*8;
      float4 a0 = *(const float4*)(xr + k0);
      float4 a1 = *(const float4*)(xr + k0 + 4);
      s16x8 bx;                                  // lane l15 = row, k = quad*8+j
      bx[0]=f2bf(a0.x); bx[1]=f2bf(a0.y); bx[2]=f2bf(a0.z); bx[3]=f2bf(a0.w);
      bx[4]=f2bf(a1.x); bx[5]=f2bf(a1.y); bx[6]=f2bf(a1.z); bx[7]=f2bf(a1.w);
      #pragma unroll
      for (int c = 0; c < 4; ++c){               // Q: A=W (m=h), B=x (n=row)
        s16x8 wq = *(const s16x8*)(Wt + (c*16 + l15)*384 + k0);
        aq[c] = __builtin_amdgcn_mfma_f32_16x16x32_bf16(wq, bx, aq[c], 0, 0, 0);
      }
      #pragma unroll
      for (int c = 0; c < 4; ++c){               // K
        s16x8 wk = *(const s16x8*)(Wt + ((c+4)*16 + l15)*384 + k0);
        ak[c] = __builtin_amdgcn_mfma_f32_16x16x32_bf16(wk, bx, ak[c], 0, 0, 0);
      }
      #pragma unroll
      for (int c = 0; c < 4; ++c){               // V swapped: A=x (m=row), B=W (n=h)
        s16x8 wv = *(const s16x8*)(Wt + ((c+8)*16 + l15)*384 + k0);
        av[c] = __builtin_amdgcn_mfma_f32_16x16x32_bf16(bx, wv, av[c], 0, 0, 0);
      }
    }

    // --- epilogues.  D layout (16x16): col(n)=l15, row(m)=quad*4+i ---
    char* krow = KsB + (r0 + l15)*128;           // this lane's t-row
    const int swzr = (l15 & 7) << 4;             // (t&7)<<4, r0 % 16 == 0

    // Q bounce through own K rows (wave-private; K not yet written)
    #pragma unroll
    for (int c = 0; c < 4; ++c){
      s16x4 v;
      #pragma unroll
      for (int i = 0; i < 4; ++i) v[i] = f2bf(aq[c][i]);
      *(s16x4*)(krow + ((c*32 + quad*8) ^ swzr)) = v;
    }
    asm volatile("s_waitcnt lgkmcnt(0)" ::: "memory");
    qf0 = *(const s16x8*)(krow + ((quad*16)      ^ swzr));   // A[m=q][k=h 0..31]
    qf1 = *(const s16x8*)(krow + ((64 + quad*16) ^ swzr));   // A[m=q][k=h 32..63]
    asm volatile("s_waitcnt lgkmcnt(0)" ::: "memory");

    // K image (overwrites the bounce bytes, same wave, DS in-order)
    #pragma unroll
    for (int c = 0; c < 4; ++c){
      s16x4 v;
      #pragma unroll
      for (int i = 0; i < 4; ++i) v[i] = f2bf(ak[c][i]);
      *(s16x4*)(krow + ((c*32 + quad*8) ^ swzr)) = v;
    }
    // V image: lane holds h = c*16+l15, regs t = r0+quad*4+i
    #pragma unroll
    for (int c = 0; c < 4; ++c){
      const int h = c*16 + l15;
      s16x4 v;
      #pragma unroll
      for (int i = 0; i < 4; ++i) v[i] = f2bf(av[c][i]);
      *(s16x4*)(VtsB + h*512 + (((r0 + quad*4)*2) ^ ((h & 7) << 4))) = v;
    }
  };

  project(F0*16, qA0, qA1);
  project(F1*16, qB0, qB1);

  __syncthreads();

  // ================= Phase 2: causal attention (all in LDS) =================
  float* ob = out + (long)b*256*64;
  short* Pw = Pp[w];
  const int swz = (l15 & 7) << 4;

  auto attend = [&](int F, s16x8 qf0, s16x8 qf1){
    const int qb = F*16;
    const int NF = F + 1;                        // causal key-frags needed (1..16)
    const int NS = (NF + 1) >> 1;                // 32-key PV steps

    f32x4 sc[16];
    #pragma unroll
    for (int f = 0; f < 16; ++f){
      f32x4 a;
      #pragma unroll
      for (int r = 0; r < 4; ++r) a[r] = 0.0f;
      if (f < NF){
        const char* kp = KsB + (f*16 + l15)*128;
        s16x8 k0v = *(const s16x8*)(kp + ((quad*16)      ^ swz));
        s16x8 k1v = *(const s16x8*)(kp + ((64 + quad*16) ^ swz));
        a = __builtin_amdgcn_mfma_f32_16x16x32_bf16(qf0, k0v, a, 0, 0, 0);
        a = __builtin_amdgcn_mfma_f32_16x16x32_bf16(qf1, k1v, a, 0, 0, 0);
      }
      sc[f] = a;
    }

    // softmax: C col=key=f*16+l15, row=q=quad*4+r
    float mx[4], sm[4];
    #pragma unroll
    for (int r = 0; r < 4; ++r) mx[r] = -3.0e38f;
    #pragma unroll
    for (int f = 0; f < 16; ++f){
      if (f < NF){
        const int key = f*16 + l15;
        #pragma unroll
        for (int r = 0; r < 4; ++r){
          const int qg = qb + quad*4 + r;
          float s = sc[f][r] * 0.125f;           // d^-0.5, H=64
          s = (key <= qg) ? s : -1.0e30f;
          sc[f][r] = s;
          mx[r] = fmaxf(mx[r], s);
        }
      }
    }
    #pragma unroll
    for (int r = 0; r < 4; ++r){
      #pragma unroll
      for (int off = 1; off < 16; off <<= 1) mx[r] = fmaxf(mx[r], __shfl_xor(mx[r], off, 16));
    }
    #pragma unroll
    for (int r = 0; r < 4; ++r) sm[r] = 0.0f;
    #pragma unroll
    for (int f = 0; f < 16; ++f){
      if (f < NF){
        #pragma unroll
        for (int r = 0; r < 4; ++r){
          float p = exp2f((sc[f][r] - mx[r]) * 1.44269504f);
          sc[f][r] = p;
          sm[r] += p;
        }
      }
    }
    #pragma unroll
    for (int r = 0; r < 4; ++r){
      #pragma unroll
      for (int off = 1; off < 16; off <<= 1) sm[r] += __shfl_xor(sm[r], off, 16);
    }

    // PV: A = P (LDS round-trip C->A layout), B = Vts rows (swizzled)
    f32x4 o[4];
    #pragma unroll
    for (int h0 = 0; h0 < 4; ++h0)
      #pragma unroll
      for (int r = 0; r < 4; ++r) o[h0][r] = 0.0f;

    #pragma unroll
    for (int ks = 0; ks < 8; ++ks){
      if (ks < NS){
        #pragma unroll
        for (int fi = 0; fi < 2; ++fi){
          const int f = 2*ks + fi;
          #pragma unroll
          for (int r = 0; r < 4; ++r){
            short v = 0;
            if (f < NF) v = f2bf(sc[f][r]);
            Pw[(quad*4 + r)*40 + fi*16 + l15] = v;
          }
        }
        s16x8 pf = *(const s16x8*)(Pw + l15*40 + quad*8);   // A[m=q][k]
        #pragma unroll
        for (int h0 = 0; h0 < 4; ++h0){
          const char* vp = VtsB + (h0*16 + l15)*512;
          s16x8 vf = *(const s16x8*)(vp + ((ks*64 + quad*16) ^ swz));
          o[h0] = __builtin_amdgcn_mfma_f32_16x16x32_bf16(pf, vf, o[h0], 0, 0, 0);
        }
      }
    }

    #pragma unroll
    for (int r = 0; r < 4; ++r){
      const float inv = 1.0f / sm[r];
      #pragma unroll
      for (int h0 = 0; h0 < 4; ++h0)
        ob[(qb + quad*4 + r)*64 + h0*16 + l15] = o[h0][r] * inv;
    }
  };

  attend(F0, qA0, qA1);
  attend(F1, qB0, qB1);
}

extern "C" void kernel_launch(void* const* d_in, const int* in_sizes, int n_in,
                              void* d_out, int out_size, void* d_ws, size_t ws_size,
                              hipStream_t stream){
  const float* x  = (const float*)d_in[0];
  const float* Wq = (const float*)d_in[1];
  const float* Wk = (const float*)d_in[2];
  const float* Wv = (const float*)d_in[3];
  float* out = (float*)d_out;

  short* Wt = (short*)d_ws;                      // 192*384*2 = 147456 B

  hipLaunchKernelGGL(wt_prep_kernel, dim3(288), dim3(256), 0, stream, Wq, Wk, Wv, Wt);
  hipLaunchKernelGGL(fused2_kernel,  dim3(512), dim3(512), 0, stream, x, Wt, out);
}

// Round 3
// 364.188 us; speedup vs baseline: 1.1646x; 1.0875x over previous
//
#include <hip/hip_runtime.h>

typedef __attribute__((ext_vector_type(4)))  float f32x4;
typedef __attribute__((ext_vector_type(16))) float f32x16;
typedef __attribute__((ext_vector_type(8)))  short s16x8;
typedef __attribute__((ext_vector_type(4)))  short s16x4;

// B=512, T=256, E=384, H=64.

__device__ inline short f2bf(float f){
  unsigned u = __float_as_uint(f);
  u = u + 0x7fffu + ((u >> 16) & 1u);   // round-to-nearest-even
  return (short)(u >> 16);
}

__device__ __forceinline__ void gld16(const void* g, void* l){
  __builtin_amdgcn_global_load_lds((const __attribute__((address_space(1))) void*)g,
                                   (__attribute__((address_space(3))) void*)l, 16, 0, 0);
}

// ---------------- Kernel 0: Wt[n][k] = W_{n/64}[k][n%64]  (bf16) ----------------
__global__ void wt_prep_kernel(const float* __restrict__ Wq, const float* __restrict__ Wk,
                               const float* __restrict__ Wv, short* __restrict__ Wt){
  int o = blockIdx.x * 256 + threadIdx.x;
  if (o >= 192*384) return;
  int n = o / 384, k = o - n*384;
  const float* W = (n < 64) ? Wq : (n < 128) ? Wk : Wv;
  Wt[o] = f2bf(W[k*64 + (n & 63)]);
}

// ---------------- Kernel A: QKV projection v2 — LDS-staged x ----------------
// Fixes the round-0..2 bottleneck: x was loaded as per-lane row gathers
// (32 cache lines per instruction -> CU miss-queue saturation). Here x is
// staged into LDS via global_load_lds with COALESCED, pre-swizzled source
// addresses, double-buffered over 12 k-chunks of 32.
// Block = 512 thr (8 waves), tile = 128 t x 192 n, grid = 1024 (b, t-half).
// Wave (wn=w>>2, wt=w&3): rows 32*wt.., cols 96*wn.. (3x 32x32x16 MFMA acc).
// wn==0: acc = {Q0,Q1,Klow}; wn==1: acc = {Khigh, Vlow(sw), Vhigh(sw)} where
// (sw) = operand-swapped mfma(bx,wv) so the accumulator is h-major for the
// [h][t] V image. Q/K/V written in the round-1 harness-verified image formats:
//   Q: [b][t][h] row-major bf16
//   K: [b][t][128B row], byte = h*2 ^ ((t&7)<<4)
//   V: [b][h][512B row], byte = t*2 ^ ((h&7)<<4)
__global__ __launch_bounds__(512, 4) void qkv2_kernel(const float* __restrict__ x,
    const short* __restrict__ Wt, short* __restrict__ Qg,
    short* __restrict__ Kg, short* __restrict__ Vg){
  __shared__ __align__(16) float xs[2][128][32];   // 2 x 16 KB chunk buffers

  const int tid  = threadIdx.x;
  const int w    = tid >> 6, lane = tid & 63;
  const int l31  = lane & 31, hh = lane >> 5;
  const int wn   = w >> 2,  wt = w & 3;
  const int b    = blockIdx.x >> 1;
  const int t0   = (blockIdx.x & 1) << 7;

  const char* xbase = (const char*)x + ((long)b*256 + t0)*1536;

  // LDS[r][cb] = x[r][cb ^ ((r&7)<<4)] ; r&7 == lane>>3 inside each 8-row inst.
  auto stage = [&](int kt, int buf){
    #pragma unroll
    for (int i2 = 0; i2 < 2; ++i2){
      const int ii = w*2 + i2;                    // 0..15, 8 rows each
      const int r  = ii*8 + (lane >> 3);
      const char* src = xbase + (long)r*1536 + kt*128
                      + ((((lane & 7) ^ (lane >> 3)) << 4));
      gld16(src, (char*)&xs[buf][ii*8][0]);
    }
  };

  f32x16 acc[3];
  #pragma unroll
  for (int c = 0; c < 3; ++c)
    #pragma unroll
    for (int i = 0; i < 16; ++i) acc[c][i] = 0.0f;

  const int swr = (l31 & 7) << 4;
  const short* wrow = Wt + (wn*96 + l31)*384;

  stage(0, 0);
  __syncthreads();

  for (int kt = 0; kt < 12; ++kt){
    if (kt < 11) stage(kt + 1, (kt + 1) & 1);

    const char* bp = (const char*)&xs[kt & 1][wt*32 + l31][0];
    #pragma unroll
    for (int s = 0; s < 2; ++s){
      const int c0 = s*64 + hh*32;
      f32x4 a0 = *(const f32x4*)(bp + ((c0     ) ^ swr));
      f32x4 a1 = *(const f32x4*)(bp + ((c0 + 16) ^ swr));
      s16x8 bx;                                   // lane l31 = row, k = hh*8 + j
      bx[0]=f2bf(a0[0]); bx[1]=f2bf(a0[1]); bx[2]=f2bf(a0[2]); bx[3]=f2bf(a0[3]);
      bx[4]=f2bf(a1[0]); bx[5]=f2bf(a1[1]); bx[6]=f2bf(a1[2]); bx[7]=f2bf(a1[3]);

      const short* wp = wrow + kt*32 + s*16 + hh*8;
      s16x8 w0 = *(const s16x8*)(wp);
      s16x8 w1 = *(const s16x8*)(wp + 32*384);
      s16x8 w2 = *(const s16x8*)(wp + 64*384);
      if (wn == 0){
        acc[0] = __builtin_amdgcn_mfma_f32_32x32x16_bf16(w0, bx, acc[0], 0, 0, 0);
        acc[1] = __builtin_amdgcn_mfma_f32_32x32x16_bf16(w1, bx, acc[1], 0, 0, 0);
        acc[2] = __builtin_amdgcn_mfma_f32_32x32x16_bf16(w2, bx, acc[2], 0, 0, 0);
      } else {
        acc[0] = __builtin_amdgcn_mfma_f32_32x32x16_bf16(w0, bx, acc[0], 0, 0, 0);
        acc[1] = __builtin_amdgcn_mfma_f32_32x32x16_bf16(bx, w1, acc[1], 0, 0, 0);
        acc[2] = __builtin_amdgcn_mfma_f32_32x32x16_bf16(bx, w2, acc[2], 0, 0, 0);
      }
    }
    __syncthreads();
  }

  // ---- epilogue.  32x32 C layout: col = l31, row m(i) = (i&3)+8*(i>>2)+4*hh ----
  const int tl = t0 + wt*32 + l31;               // this lane's t (non-swapped accs)
  short* Qb = Qg + (long)b*16384;
  char*  Kb = (char*)(Kg + (long)b*16384);
  char*  Vb = (char*)(Vg + (long)b*16384);

  if (wn == 0){
    #pragma unroll
    for (int c = 0; c < 2; ++c)                  // Q: h = c*32 + 8g + 4hh + j
      #pragma unroll
      for (int g = 0; g < 4; ++g){
        s16x4 v;
        #pragma unroll
        for (int j = 0; j < 4; ++j) v[j] = f2bf(acc[c][4*g + j]);
        *(s16x4*)(Qb + (long)tl*64 + c*32 + 8*g + 4*hh) = v;
      }
    const int swk = (tl & 7) << 4;               // K low: h = 8g + 4hh + j
    #pragma unroll
    for (int g = 0; g < 4; ++g){
      s16x4 v;
      #pragma unroll
      for (int j = 0; j < 4; ++j) v[j] = f2bf(acc[2][4*g + j]);
      *(s16x4*)(Kb + (long)tl*128 + ((16*g + 8*hh) ^ swk)) = v;
    }
  } else {
    const int swk = (tl & 7) << 4;               // K high: h = 32 + 8g + 4hh + j
    #pragma unroll
    for (int g = 0; g < 4; ++g){
      s16x4 v;
      #pragma unroll
      for (int j = 0; j < 4; ++j) v[j] = f2bf(acc[0][4*g + j]);
      *(s16x4*)(Kb + (long)tl*128 + ((64 + 16*g + 8*hh) ^ swk)) = v;
    }
    #pragma unroll
    for (int c = 1; c < 3; ++c){                 // V swapped: lane = h-col
      const int h   = (c - 1)*32 + l31;
      const int swv = (h & 7) << 4;
      #pragma unroll
      for (int g = 0; g < 4; ++g){               // t = t0+32wt+8g+4hh+j
        const int tb = t0 + wt*32 + 8*g + 4*hh;
        s16x4 v;
        #pragma unroll
        for (int j = 0; j < 4; ++j) v[j] = f2bf(acc[c][4*g + j]);
        *(s16x4*)(Vb + (long)h*512 + ((tb*2) ^ swv)) = v;
      }
    }
  }
}

// ---------------- Kernel B: causal attention (round-1 verified) ----------------
__global__ __launch_bounds__(512, 4) void attn_kernel(const short* __restrict__ Qg,
    const short* __restrict__ Kg, const short* __restrict__ Vg,
    float* __restrict__ out){
  __shared__ __align__(16) short Ks[16384];     // 32768 B swizzled [t][h] image
  __shared__ __align__(16) short Vts[16384];    // 32768 B swizzled [h][t] image
  __shared__ __align__(16) short Pp[8][16*40];  // 10240 B per-wave P scratch

  const int tid  = threadIdx.x;
  const int w    = tid >> 6, lane = tid & 63;
  const int l15  = lane & 15, quad = lane >> 4;
  const int b    = blockIdx.x;

  const short* Qb = Qg + (long)b*16384;
  const int F0 = w, F1 = 15 - w;
  s16x8 qA0 = *(const s16x8*)(Qb + (F0*16 + l15)*64 + quad*8);
  s16x8 qA1 = *(const s16x8*)(Qb + (F0*16 + l15)*64 + 32 + quad*8);
  s16x8 qB0 = *(const s16x8*)(Qb + (F1*16 + l15)*64 + quad*8);
  s16x8 qB1 = *(const s16x8*)(Qb + (F1*16 + l15)*64 + 32 + quad*8);

  const char* Kb = (const char*)(Kg + (long)b*16384);
  const char* Vb = (const char*)(Vg + (long)b*16384);
  {
    const int base = w*4096;
    #pragma unroll
    for (int i = 0; i < 4; ++i){
      gld16(Kb + base + i*1024 + lane*16, (char*)Ks  + base + i*1024);
      gld16(Vb + base + i*1024 + lane*16, (char*)Vts + base + i*1024);
    }
  }
  __syncthreads();

  float* ob = out + (long)b*256*64;
  short* Pw = Pp[w];
  const int swz = (l15 & 7) << 4;

  auto attend = [&](int F, s16x8 qf0, s16x8 qf1){
    const int qb = F*16;
    const int NF = F + 1;
    const int NS = (NF + 1) >> 1;

    f32x4 sc[16];
    #pragma unroll
    for (int f = 0; f < 16; ++f){
      f32x4 a;
      #pragma unroll
      for (int r = 0; r < 4; ++r) a[r] = 0.0f;
      if (f < NF){
        const char* kp = (const char*)Ks + (f*16 + l15)*128;
        s16x8 k0v = *(const s16x8*)(kp + ((quad*16)      ^ swz));
        s16x8 k1v = *(const s16x8*)(kp + ((64 + quad*16) ^ swz));
        a = __builtin_amdgcn_mfma_f32_16x16x32_bf16(qf0, k0v, a, 0, 0, 0);
        a = __builtin_amdgcn_mfma_f32_16x16x32_bf16(qf1, k1v, a, 0, 0, 0);
      }
      sc[f] = a;
    }

    float mx[4], sm[4];
    #pragma unroll
    for (int r = 0; r < 4; ++r) mx[r] = -3.0e38f;
    #pragma unroll
    for (int f = 0; f < 16; ++f){
      if (f < NF){
        const int key = f*16 + l15;
        #pragma unroll
        for (int r = 0; r < 4; ++r){
          const int qg = qb + quad*4 + r;
          float s = sc[f][r] * 0.125f;
          s = (key <= qg) ? s : -1.0e30f;
          sc[f][r] = s;
          mx[r] = fmaxf(mx[r], s);
        }
      }
    }
    #pragma unroll
    for (int r = 0; r < 4; ++r){
      #pragma unroll
      for (int off = 1; off < 16; off <<= 1) mx[r] = fmaxf(mx[r], __shfl_xor(mx[r], off, 16));
    }
    #pragma unroll
    for (int r = 0; r < 4; ++r) sm[r] = 0.0f;
    #pragma unroll
    for (int f = 0; f < 16; ++f){
      if (f < NF){
        #pragma unroll
        for (int r = 0; r < 4; ++r){
          float p = exp2f((sc[f][r] - mx[r]) * 1.44269504f);
          sc[f][r] = p;
          sm[r] += p;
        }
      }
    }
    #pragma unroll
    for (int r = 0; r < 4; ++r){
      #pragma unroll
      for (int off = 1; off < 16; off <<= 1) sm[r] += __shfl_xor(sm[r], off, 16);
    }

    f32x4 o[4];
    #pragma unroll
    for (int h0 = 0; h0 < 4; ++h0)
      #pragma unroll
      for (int r = 0; r < 4; ++r) o[h0][r] = 0.0f;

    #pragma unroll
    for (int ks = 0; ks < 8; ++ks){
      if (ks < NS){
        #pragma unroll
        for (int fi = 0; fi < 2; ++fi){
          const int f = 2*ks + fi;
          #pragma unroll
          for (int r = 0; r < 4; ++r){
            short v = 0;
            if (f < NF) v = f2bf(sc[f][r]);
            Pw[(quad*4 + r)*40 + fi*16 + l15] = v;
          }
        }
        s16x8 pf = *(const s16x8*)(Pw + l15*40 + quad*8);
        #pragma unroll
        for (int h0 = 0; h0 < 4; ++h0){
          const char* vp = (const char*)Vts + (h0*16 + l15)*512;
          s16x8 vf = *(const s16x8*)(vp + ((ks*64 + quad*16) ^ swz));
          o[h0] = __builtin_amdgcn_mfma_f32_16x16x32_bf16(pf, vf, o[h0], 0, 0, 0);
        }
      }
    }

    #pragma unroll
    for (int r = 0; r < 4; ++r){
      const float inv = 1.0f / sm[r];
      #pragma unroll
      for (int h0 = 0; h0 < 4; ++h0)
        ob[(qb + quad*4 + r)*64 + h0*16 + l15] = o[h0][r] * inv;
    }
  };
  attend(F0, qA0, qA1);
  attend(F1, qB0, qB1);
}

// ---------------- Fallback (ws too small): round-2 fused kernel ----------------
__global__ __launch_bounds__(512, 4) void fused2_kernel(const float* __restrict__ x,
                             const short* __restrict__ Wt, float* __restrict__ out){
  __shared__ __align__(16) char  KsB[32768];
  __shared__ __align__(16) char  VtsB[32768];
  __shared__ __align__(16) short Pp[8][16*40];

  const int tid  = threadIdx.x;
  const int w    = tid >> 6, lane = tid & 63;
  const int l15  = lane & 15, quad = lane >> 4;
  const int b    = blockIdx.x;

  const float* xb = x + (long)b*256*384;
  const int F0 = w, F1 = 15 - w;

  s16x8 qA0, qA1, qB0, qB1;

  auto project = [&](int r0, s16x8& qf0, s16x8& qf1){
    f32x4 aq[4], ak[4], av[4];
    #pragma unroll
    for (int c = 0; c < 4; ++c)
      #pragma unroll
      for (int i = 0; i < 4; ++i){ aq[c][i]=0.f; ak[c][i]=0.f; av[c][i]=0.f; }

    const float* xr = xb + (long)(r0 + l15)*384;
    #pragma unroll 2
    for (int kt = 0; kt < 12; ++kt){
      const int k0 = kt*32 + quad*8;
      float4 a0 = *(const float4*)(xr + k0);
      float4 a1 = *(const float4*)(xr + k0 + 4);
      s16x8 bx;
      bx[0]=f2bf(a0.x); bx[1]=f2bf(a0.y); bx[2]=f2bf(a0.z); bx[3]=f2bf(a0.w);
      bx[4]=f2bf(a1.x); bx[5]=f2bf(a1.y); bx[6]=f2bf(a1.z); bx[7]=f2bf(a1.w);
      #pragma unroll
      for (int c = 0; c < 4; ++c){
        s16x8 wq = *(const s16x8*)(Wt + (c*16 + l15)*384 + k0);
        aq[c] = __builtin_amdgcn_mfma_f32_16x16x32_bf16(wq, bx, aq[c], 0, 0, 0);
      }
      #pragma unroll
      for (int c = 0; c < 4; ++c){
        s16x8 wk = *(const s16x8*)(Wt + ((c+4)*16 + l15)*384 + k0);
        ak[c] = __builtin_amdgcn_mfma_f32_16x16x32_bf16(wk, bx, ak[c], 0, 0, 0);
      }
      #pragma unroll
      for (int c = 0; c < 4; ++c){
        s16x8 wv = *(const s16x8*)(Wt + ((c+8)*16 + l15)*384 + k0);
        av[c] = __builtin_amdgcn_mfma_f32_16x16x32_bf16(bx, wv, av[c], 0, 0, 0);
      }
    }

    char* krow = KsB + (r0 + l15)*128;
    const int swzr = (l15 & 7) << 4;

    #pragma unroll
    for (int c = 0; c < 4; ++c){
      s16x4 v;
      #pragma unroll
      for (int i = 0; i < 4; ++i) v[i] = f2bf(aq[c][i]);
      *(s16x4*)(krow + ((c*32 + quad*8) ^ swzr)) = v;
    }
    asm volatile("s_waitcnt lgkmcnt(0)" ::: "memory");
    qf0 = *(const s16x8*)(krow + ((quad*16)      ^ swzr));
    qf1 = *(const s16x8*)(krow + ((64 + quad*16) ^ swzr));
    asm volatile("s_waitcnt lgkmcnt(0)" ::: "memory");

    #pragma unroll
    for (int c = 0; c < 4; ++c){
      s16x4 v;
      #pragma unroll
      for (int i = 0; i < 4; ++i) v[i] = f2bf(ak[c][i]);
      *(s16x4*)(krow + ((c*32 + quad*8) ^ swzr)) = v;
    }
    #pragma unroll
    for (int c = 0; c < 4; ++c){
      const int h = c*16 + l15;
      s16x4 v;
      #pragma unroll
      for (int i = 0; i < 4; ++i) v[i] = f2bf(av[c][i]);
      *(s16x4*)(VtsB + h*512 + (((r0 + quad*4)*2) ^ ((h & 7) << 4))) = v;
    }
  };

  project(F0*16, qA0, qA1);
  project(F1*16, qB0, qB1);

  __syncthreads();

  float* ob = out + (long)b*256*64;
  short* Pw = Pp[w];
  const int swz = (l15 & 7) << 4;

  auto attend = [&](int F, s16x8 qf0, s16x8 qf1){
    const int qb = F*16;
    const int NF = F + 1;
    const int NS = (NF + 1) >> 1;

    f32x4 sc[16];
    #pragma unroll
    for (int f = 0; f < 16; ++f){
      f32x4 a;
      #pragma unroll
      for (int r = 0; r < 4; ++r) a[r] = 0.0f;
      if (f < NF){
        const char* kp = KsB + (f*16 + l15)*128;
        s16x8 k0v = *(const s16x8*)(kp + ((quad*16)      ^ swz));
        s16x8 k1v = *(const s16x8*)(kp + ((64 + quad*16) ^ swz));
        a = __builtin_amdgcn_mfma_f32_16x16x32_bf16(qf0, k0v, a, 0, 0, 0);
        a = __builtin_amdgcn_mfma_f32_16x16x32_bf16(qf1, k1v, a, 0, 0, 0);
      }
      sc[f] = a;
    }

    float mx[4], sm[4];
    #pragma unroll
    for (int r = 0; r < 4; ++r) mx[r] = -3.0e38f;
    #pragma unroll
    for (int f = 0; f < 16; ++f){
      if (f < NF){
        const int key = f*16 + l15;
        #pragma unroll
        for (int r = 0; r < 4; ++r){
          const int qg = qb + quad*4 + r;
          float s = sc[f][r] * 0.125f;
          s = (key <= qg) ? s : -1.0e30f;
          sc[f][r] = s;
          mx[r] = fmaxf(mx[r], s);
        }
      }
    }
    #pragma unroll
    for (int r = 0; r < 4; ++r){
      #pragma unroll
      for (int off = 1; off < 16; off <<= 1) mx[r] = fmaxf(mx[r], __shfl_xor(mx[r], off, 16));
    }
    #pragma unroll
    for (int r = 0; r < 4; ++r) sm[r] = 0.0f;
    #pragma unroll
    for (int f = 0; f < 16; ++f){
      if (f < NF){
        #pragma unroll
        for (int r = 0; r < 4; ++r){
          float p = exp2f((sc[f][r] - mx[r]) * 1.44269504f);
          sc[f][r] = p;
          sm[r] += p;
        }
      }
    }
    #pragma unroll
    for (int r = 0; r < 4; ++r){
      #pragma unroll
      for (int off = 1; off < 16; off <<= 1) sm[r] += __shfl_xor(sm[r], off, 16);
    }

    f32x4 o[4];
    #pragma unroll
    for (int h0 = 0; h0 < 4; ++h0)
      #pragma unroll
      for (int r = 0; r < 4; ++r) o[h0][r] = 0.0f;

    #pragma unroll
    for (int ks = 0; ks < 8; ++ks){
      if (ks < NS){
        #pragma unroll
        for (int fi = 0; fi < 2; ++fi){
          const int f = 2*ks + fi;
          #pragma unroll
          for (int r = 0; r < 4; ++r){
            short v = 0;
            if (f < NF) v = f2bf(sc[f][r]);
            Pw[(quad*4 + r)*40 + fi*16 + l15] = v;
          }
        }
        s16x8 pf = *(const s16x8*)(Pw + l15*40 + quad*8);
        #pragma unroll
        for (int h0 = 0; h0 < 4; ++h0){
          const char* vp = VtsB + (h0*16 + l15)*512;
          s16x8 vf = *(const s16x8*)(vp + ((ks*64 + quad*16) ^ swz));
          o[h0] = __builtin_amdgcn_mfma_f32_16x16x32_bf16(pf, vf, o[h0], 0, 0, 0);
        }
      }
    }

    #pragma unroll
    for (int r = 0; r < 4; ++r){
      const float inv = 1.0f / sm[r];
      #pragma unroll
      for (int h0 = 0; h0 < 4; ++h0)
        ob[(qb + quad*4 + r)*64 + h0*16 + l15] = o[h0][r] * inv;
    }
  };

  attend(F0, qA0, qA1);
  attend(F1, qB0, qB1);
}

extern "C" void kernel_launch(void* const* d_in, const int* in_sizes, int n_in,
                              void* d_out, int out_size, void* d_ws, size_t ws_size,
                              hipStream_t stream){
  const float* x  = (const float*)d_in[0];
  const float* Wq = (const float*)d_in[1];
  const float* Wk = (const float*)d_in[2];
  const float* Wv = (const float*)d_in[3];
  float* out = (float*)d_out;

  short* Wt = (short*)d_ws;                        // 192*384*2 = 147456 B
  const size_t need = 147456 + 3ull*16777216ull;   // Wt + Q/K/V bf16 images

  hipLaunchKernelGGL(wt_prep_kernel, dim3(288), dim3(256), 0, stream, Wq, Wk, Wv, Wt);
  if (ws_size >= need){
    short* Qg = (short*)((char*)d_ws + 147456);
    short* Kg = Qg + 8388608;
    short* Vg = Kg + 8388608;
    hipLaunchKernelGGL(qkv2_kernel, dim3(1024), dim3(512), 0, stream, x, Wt, Qg, Kg, Vg);
    hipLaunchKernelGGL(attn_kernel, dim3(512),  dim3(512), 0, stream, Qg, Kg, Vg, out);
  } else {
    hipLaunchKernelGGL(fused2_kernel, dim3(512), dim3(512), 0, stream, x, Wt, out);
  }
}

// Round 4
// 353.086 us; speedup vs baseline: 1.2013x; 1.0314x over previous
//
#include <hip/hip_runtime.h>

typedef __attribute__((ext_vector_type(4)))  float f32x4;
typedef __attribute__((ext_vector_type(16))) float f32x16;
typedef __attribute__((ext_vector_type(8)))  short s16x8;
typedef __attribute__((ext_vector_type(4)))  short s16x4;

// B=512, T=256, E=384, H=64.

__device__ inline short f2bf(float f){
  unsigned u = __float_as_uint(f);
  u = u + 0x7fffu + ((u >> 16) & 1u);   // round-to-nearest-even
  return (short)(u >> 16);
}

// 8x f32 -> 8x bf16 via v_cvt_pk_bf16_f32 (RNE, bit-identical to f2bf)
__device__ __forceinline__ s16x8 pack8(f32x4 a0, f32x4 a1){
  union { s16x8 v; unsigned u[4]; } r;
  asm("v_cvt_pk_bf16_f32 %0, %1, %2" : "=v"(r.u[0]) : "v"(a0[0]), "v"(a0[1]));
  asm("v_cvt_pk_bf16_f32 %0, %1, %2" : "=v"(r.u[1]) : "v"(a0[2]), "v"(a0[3]));
  asm("v_cvt_pk_bf16_f32 %0, %1, %2" : "=v"(r.u[2]) : "v"(a1[0]), "v"(a1[1]));
  asm("v_cvt_pk_bf16_f32 %0, %1, %2" : "=v"(r.u[3]) : "v"(a1[2]), "v"(a1[3]));
  return r.v;
}

__device__ __forceinline__ void gld16(const void* g, void* l){
  __builtin_amdgcn_global_load_lds((const __attribute__((address_space(1))) void*)g,
                                   (__attribute__((address_space(3))) void*)l, 16, 0, 0);
}

// ---------------- Kernel 0: Wt[n][k] = W_{n/64}[k][n%64]  (bf16) ----------------
__global__ void wt_prep_kernel(const float* __restrict__ Wq, const float* __restrict__ Wk,
                               const float* __restrict__ Wv, short* __restrict__ Wt){
  int o = blockIdx.x * 256 + threadIdx.x;
  if (o >= 192*384) return;
  int n = o / 384, k = o - n*384;
  const float* W = (n < 64) ? Wq : (n < 128) ? Wk : Wv;
  Wt[o] = f2bf(W[k*64 + (n & 63)]);
}

// ---------------- Kernel A: QKV projection v3 — pipelined staging ----------------
// Same tile/layout math as the verified qkv2, but the per-iteration
// __syncthreads() (which drains vmcnt to 0 and kills the prefetch) is replaced
// by counted `s_waitcnt vmcnt(10)` + raw s_barrier, with 4 LDS x-buffers and
// 3-deep staging. Per-iter issue order is fixed: [Wt-prefetch(kt+1): 6 loads,
// stage(kt+3): 2 gld16] so that >=10 vmcnt ops are always issued after
// stage(kt) at its wait point -> vmcnt(10) retires exactly stage(kt)
// (in-order vmcnt retire). Wt fragments are register-prefetched one iteration
// ahead (two named register sets, unroll-by-2).
__global__ __launch_bounds__(512, 4) void qkv3_kernel(const float* __restrict__ x,
    const short* __restrict__ Wt, short* __restrict__ Qg,
    short* __restrict__ Kg, short* __restrict__ Vg){
  __shared__ __align__(16) float xs[4][128][32];   // 4 x 16 KB chunk buffers

  const int tid  = threadIdx.x;
  const int w    = tid >> 6, lane = tid & 63;
  const int l31  = lane & 31, hh = lane >> 5;
  const int wn   = w >> 2,  wt = w & 3;
  const int b    = blockIdx.x >> 1;
  const int t0   = (blockIdx.x & 1) << 7;

  const char* xbase = (const char*)x + ((long)b*256 + t0)*1536;

  // LDS[r][cb] = x[r][cb ^ ((r&7)<<4)] ; linear dest, inverse-swizzled source.
  auto stage = [&](int kt, int buf){
    #pragma unroll
    for (int i2 = 0; i2 < 2; ++i2){
      const int ii = w*2 + i2;                    // 0..15, 8 rows each
      const int r  = ii*8 + (lane >> 3);
      const char* src = xbase + (long)r*1536 + kt*128
                      + ((((lane & 7) ^ (lane >> 3)) << 4));
      gld16(src, (char*)&xs[buf][ii*8][0]);
    }
  };

  f32x16 acc[3];
  #pragma unroll
  for (int c = 0; c < 3; ++c)
    #pragma unroll
    for (int i = 0; i < 16; ++i) acc[c][i] = 0.0f;

  const int swr = (l31 & 7) << 4;
  const short* wrow = Wt + (wn*96 + l31)*384;

  // 6 Wt fragment loads for chunk kt (s=0 set: a*, s=1 set: b*)
  auto loadWt = [&](int kt, s16x8& a0, s16x8& a1, s16x8& a2,
                            s16x8& b0, s16x8& b1, s16x8& b2){
    const short* wp0 = wrow + kt*32 + hh*8;
    a0 = *(const s16x8*)(wp0);
    a1 = *(const s16x8*)(wp0 + 32*384);
    a2 = *(const s16x8*)(wp0 + 64*384);
    const short* wp1 = wp0 + 16;
    b0 = *(const s16x8*)(wp1);
    b1 = *(const s16x8*)(wp1 + 32*384);
    b2 = *(const s16x8*)(wp1 + 64*384);
  };

  auto compute = [&](int kt, s16x8 w0a, s16x8 w1a, s16x8 w2a,
                             s16x8 w0b, s16x8 w1b, s16x8 w2b){
    const char* bp = (const char*)&xs[kt & 3][wt*32 + l31][0];
    {  // s = 0
      f32x4 a0 = *(const f32x4*)(bp + ((hh*32)      ^ swr));
      f32x4 a1 = *(const f32x4*)(bp + ((hh*32 + 16) ^ swr));
      s16x8 bx = pack8(a0, a1);
      if (wn == 0){
        acc[0] = __builtin_amdgcn_mfma_f32_32x32x16_bf16(w0a, bx, acc[0], 0, 0, 0);
        acc[1] = __builtin_amdgcn_mfma_f32_32x32x16_bf16(w1a, bx, acc[1], 0, 0, 0);
        acc[2] = __builtin_amdgcn_mfma_f32_32x32x16_bf16(w2a, bx, acc[2], 0, 0, 0);
      } else {
        acc[0] = __builtin_amdgcn_mfma_f32_32x32x16_bf16(w0a, bx, acc[0], 0, 0, 0);
        acc[1] = __builtin_amdgcn_mfma_f32_32x32x16_bf16(bx, w1a, acc[1], 0, 0, 0);
        acc[2] = __builtin_amdgcn_mfma_f32_32x32x16_bf16(bx, w2a, acc[2], 0, 0, 0);
      }
    }
    {  // s = 1
      f32x4 a0 = *(const f32x4*)(bp + ((64 + hh*32)      ^ swr));
      f32x4 a1 = *(const f32x4*)(bp + ((64 + hh*32 + 16) ^ swr));
      s16x8 bx = pack8(a0, a1);
      if (wn == 0){
        acc[0] = __builtin_amdgcn_mfma_f32_32x32x16_bf16(w0b, bx, acc[0], 0, 0, 0);
        acc[1] = __builtin_amdgcn_mfma_f32_32x32x16_bf16(w1b, bx, acc[1], 0, 0, 0);
        acc[2] = __builtin_amdgcn_mfma_f32_32x32x16_bf16(w2b, bx, acc[2], 0, 0, 0);
      } else {
        acc[0] = __builtin_amdgcn_mfma_f32_32x32x16_bf16(w0b, bx, acc[0], 0, 0, 0);
        acc[1] = __builtin_amdgcn_mfma_f32_32x32x16_bf16(bx, w1b, acc[1], 0, 0, 0);
        acc[2] = __builtin_amdgcn_mfma_f32_32x32x16_bf16(bx, w2b, acc[2], 0, 0, 0);
      }
    }
  };

  s16x8 A0,A1,A2,A3,A4,A5, B0,B1,B2,B3,B4,B5;

  // Prologue issue order: stage0(2), stage1(2), Wt0(6), stage2(2) = 12 ops.
  stage(0, 0);
  stage(1, 1);
  loadWt(0, A0, A1, A2, A3, A4, A5);
  stage(2, 2);

  auto step = [&](int kt,
                  s16x8& c0, s16x8& c1, s16x8& c2, s16x8& c3, s16x8& c4, s16x8& c5,
                  s16x8& n0, s16x8& n1, s16x8& n2, s16x8& n3, s16x8& n4, s16x8& n5){
    asm volatile("s_waitcnt vmcnt(10)" ::: "memory");   // stage(kt) landed
    __builtin_amdgcn_s_barrier();
    __builtin_amdgcn_sched_barrier(0);
    if (kt < 11) loadWt(kt + 1, n0, n1, n2, n3, n4, n5);
    if (kt < 9)  stage(kt + 3, (kt + 3) & 3);
    compute(kt, c0, c1, c2, c3, c4, c5);
  };

  #pragma unroll 1
  for (int k2 = 0; k2 < 6; ++k2){
    step(2*k2,     A0,A1,A2,A3,A4,A5,  B0,B1,B2,B3,B4,B5);
    step(2*k2 + 1, B0,B1,B2,B3,B4,B5,  A0,A1,A2,A3,A4,A5);
  }

  // ---- epilogue (identical to verified qkv2). C: col=l31, m(i)=(i&3)+8*(i>>2)+4*hh ----
  const int tl = t0 + wt*32 + l31;
  short* Qb = Qg + (long)b*16384;
  char*  Kb = (char*)(Kg + (long)b*16384);
  char*  Vb = (char*)(Vg + (long)b*16384);

  if (wn == 0){
    #pragma unroll
    for (int c = 0; c < 2; ++c)
      #pragma unroll
      for (int g = 0; g < 4; ++g){
        s16x4 v;
        #pragma unroll
        for (int j = 0; j < 4; ++j) v[j] = f2bf(acc[c][4*g + j]);
        *(s16x4*)(Qb + (long)tl*64 + c*32 + 8*g + 4*hh) = v;
      }
    const int swk = (tl & 7) << 4;
    #pragma unroll
    for (int g = 0; g < 4; ++g){
      s16x4 v;
      #pragma unroll
      for (int j = 0; j < 4; ++j) v[j] = f2bf(acc[2][4*g + j]);
      *(s16x4*)(Kb + (long)tl*128 + ((16*g + 8*hh) ^ swk)) = v;
    }
  } else {
    const int swk = (tl & 7) << 4;
    #pragma unroll
    for (int g = 0; g < 4; ++g){
      s16x4 v;
      #pragma unroll
      for (int j = 0; j < 4; ++j) v[j] = f2bf(acc[0][4*g + j]);
      *(s16x4*)(Kb + (long)tl*128 + ((64 + 16*g + 8*hh) ^ swk)) = v;
    }
    #pragma unroll
    for (int c = 1; c < 3; ++c){
      const int h   = (c - 1)*32 + l31;
      const int swv = (h & 7) << 4;
      #pragma unroll
      for (int g = 0; g < 4; ++g){
        const int tb = t0 + wt*32 + 8*g + 4*hh;
        s16x4 v;
        #pragma unroll
        for (int j = 0; j < 4; ++j) v[j] = f2bf(acc[c][4*g + j]);
        *(s16x4*)(Vb + (long)h*512 + ((tb*2) ^ swv)) = v;
      }
    }
  }
}

// ---------------- Kernel B: causal attention (round-1 verified) ----------------
__global__ __launch_bounds__(512, 4) void attn_kernel(const short* __restrict__ Qg,
    const short* __restrict__ Kg, const short* __restrict__ Vg,
    float* __restrict__ out){
  __shared__ __align__(16) short Ks[16384];     // 32768 B swizzled [t][h] image
  __shared__ __align__(16) short Vts[16384];    // 32768 B swizzled [h][t] image
  __shared__ __align__(16) short Pp[8][16*40];  // 10240 B per-wave P scratch

  const int tid  = threadIdx.x;
  const int w    = tid >> 6, lane = tid & 63;
  const int l15  = lane & 15, quad = lane >> 4;
  const int b    = blockIdx.x;

  const short* Qb = Qg + (long)b*16384;
  const int F0 = w, F1 = 15 - w;
  s16x8 qA0 = *(const s16x8*)(Qb + (F0*16 + l15)*64 + quad*8);
  s16x8 qA1 = *(const s16x8*)(Qb + (F0*16 + l15)*64 + 32 + quad*8);
  s16x8 qB0 = *(const s16x8*)(Qb + (F1*16 + l15)*64 + quad*8);
  s16x8 qB1 = *(const s16x8*)(Qb + (F1*16 + l15)*64 + 32 + quad*8);

  const char* Kb = (const char*)(Kg + (long)b*16384);
  const char* Vb = (const char*)(Vg + (long)b*16384);
  {
    const int base = w*4096;
    #pragma unroll
    for (int i = 0; i < 4; ++i){
      gld16(Kb + base + i*1024 + lane*16, (char*)Ks  + base + i*1024);
      gld16(Vb + base + i*1024 + lane*16, (char*)Vts + base + i*1024);
    }
  }
  __syncthreads();

  float* ob = out + (long)b*256*64;
  short* Pw = Pp[w];
  const int swz = (l15 & 7) << 4;

  auto attend = [&](int F, s16x8 qf0, s16x8 qf1){
    const int qb = F*16;
    const int NF = F + 1;
    const int NS = (NF + 1) >> 1;

    f32x4 sc[16];
    #pragma unroll
    for (int f = 0; f < 16; ++f){
      f32x4 a;
      #pragma unroll
      for (int r = 0; r < 4; ++r) a[r] = 0.0f;
      if (f < NF){
        const char* kp = (const char*)Ks + (f*16 + l15)*128;
        s16x8 k0v = *(const s16x8*)(kp + ((quad*16)      ^ swz));
        s16x8 k1v = *(const s16x8*)(kp + ((64 + quad*16) ^ swz));
        a = __builtin_amdgcn_mfma_f32_16x16x32_bf16(qf0, k0v, a, 0, 0, 0);
        a = __builtin_amdgcn_mfma_f32_16x16x32_bf16(qf1, k1v, a, 0, 0, 0);
      }
      sc[f] = a;
    }

    float mx[4], sm[4];
    #pragma unroll
    for (int r = 0; r < 4; ++r) mx[r] = -3.0e38f;
    #pragma unroll
    for (int f = 0; f < 16; ++f){
      if (f < NF){
        const int key = f*16 + l15;
        #pragma unroll
        for (int r = 0; r < 4; ++r){
          const int qg = qb + quad*4 + r;
          float s = sc[f][r] * 0.125f;
          s = (key <= qg) ? s : -1.0e30f;
          sc[f][r] = s;
          mx[r] = fmaxf(mx[r], s);
        }
      }
    }
    #pragma unroll
    for (int r = 0; r < 4; ++r){
      #pragma unroll
      for (int off = 1; off < 16; off <<= 1) mx[r] = fmaxf(mx[r], __shfl_xor(mx[r], off, 16));
    }
    #pragma unroll
    for (int r = 0; r < 4; ++r) sm[r] = 0.0f;
    #pragma unroll
    for (int f = 0; f < 16; ++f){
      if (f < NF){
        #pragma unroll
        for (int r = 0; r < 4; ++r){
          float p = exp2f((sc[f][r] - mx[r]) * 1.44269504f);
          sc[f][r] = p;
          sm[r] += p;
        }
      }
    }
    #pragma unroll
    for (int r = 0; r < 4; ++r){
      #pragma unroll
      for (int off = 1; off < 16; off <<= 1) sm[r] += __shfl_xor(sm[r], off, 16);
    }

    f32x4 o[4];
    #pragma unroll
    for (int h0 = 0; h0 < 4; ++h0)
      #pragma unroll
      for (int r = 0; r < 4; ++r) o[h0][r] = 0.0f;

    #pragma unroll
    for (int ks = 0; ks < 8; ++ks){
      if (ks < NS){
        #pragma unroll
        for (int fi = 0; fi < 2; ++fi){
          const int f = 2*ks + fi;
          #pragma unroll
          for (int r = 0; r < 4; ++r){
            short v = 0;
            if (f < NF) v = f2bf(sc[f][r]);
            Pw[(quad*4 + r)*40 + fi*16 + l15] = v;
          }
        }
        s16x8 pf = *(const s16x8*)(Pw + l15*40 + quad*8);
        #pragma unroll
        for (int h0 = 0; h0 < 4; ++h0){
          const char* vp = (const char*)Vts + (h0*16 + l15)*512;
          s16x8 vf = *(const s16x8*)(vp + ((ks*64 + quad*16) ^ swz));
          o[h0] = __builtin_amdgcn_mfma_f32_16x16x32_bf16(pf, vf, o[h0], 0, 0, 0);
        }
      }
    }

    #pragma unroll
    for (int r = 0; r < 4; ++r){
      const float inv = 1.0f / sm[r];
      #pragma unroll
      for (int h0 = 0; h0 < 4; ++h0)
        ob[(qb + quad*4 + r)*64 + h0*16 + l15] = o[h0][r] * inv;
    }
  };
  attend(F0, qA0, qA1);
  attend(F1, qB0, qB1);
}

// ---------------- Fallback (ws too small): round-2 fused kernel ----------------
__global__ __launch_bounds__(512, 4) void fused2_kernel(const float* __restrict__ x,
                             const short* __restrict__ Wt, float* __restrict__ out){
  __shared__ __align__(16) char  KsB[32768];
  __shared__ __align__(16) char  VtsB[32768];
  __shared__ __align__(16) short Pp[8][16*40];

  const int tid  = threadIdx.x;
  const int w    = tid >> 6, lane = tid & 63;
  const int l15  = lane & 15, quad = lane >> 4;
  const int b    = blockIdx.x;

  const float* xb = x + (long)b*256*384;
  const int F0 = w, F1 = 15 - w;

  s16x8 qA0, qA1, qB0, qB1;

  auto project = [&](int r0, s16x8& qf0, s16x8& qf1){
    f32x4 aq[4], ak[4], av[4];
    #pragma unroll
    for (int c = 0; c < 4; ++c)
      #pragma unroll
      for (int i = 0; i < 4; ++i){ aq[c][i]=0.f; ak[c][i]=0.f; av[c][i]=0.f; }

    const float* xr = xb + (long)(r0 + l15)*384;
    #pragma unroll 2
    for (int kt = 0; kt < 12; ++kt){
      const int k0 = kt*32 + quad*8;
      float4 a0 = *(const float4*)(xr + k0);
      float4 a1 = *(const float4*)(xr + k0 + 4);
      s16x8 bx;
      bx[0]=f2bf(a0.x); bx[1]=f2bf(a0.y); bx[2]=f2bf(a0.z); bx[3]=f2bf(a0.w);
      bx[4]=f2bf(a1.x); bx[5]=f2bf(a1.y); bx[6]=f2bf(a1.z); bx[7]=f2bf(a1.w);
      #pragma unroll
      for (int c = 0; c < 4; ++c){
        s16x8 wq = *(const s16x8*)(Wt + (c*16 + l15)*384 + k0);
        aq[c] = __builtin_amdgcn_mfma_f32_16x16x32_bf16(wq, bx, aq[c], 0, 0, 0);
      }
      #pragma unroll
      for (int c = 0; c < 4; ++c){
        s16x8 wk = *(const s16x8*)(Wt + ((c+4)*16 + l15)*384 + k0);
        ak[c] = __builtin_amdgcn_mfma_f32_16x16x32_bf16(wk, bx, ak[c], 0, 0, 0);
      }
      #pragma unroll
      for (int c = 0; c < 4; ++c){
        s16x8 wv = *(const s16x8*)(Wt + ((c+8)*16 + l15)*384 + k0);
        av[c] = __builtin_amdgcn_mfma_f32_16x16x32_bf16(bx, wv, av[c], 0, 0, 0);
      }
    }

    char* krow = KsB + (r0 + l15)*128;
    const int swzr = (l15 & 7) << 4;

    #pragma unroll
    for (int c = 0; c < 4; ++c){
      s16x4 v;
      #pragma unroll
      for (int i = 0; i < 4; ++i) v[i] = f2bf(aq[c][i]);
      *(s16x4*)(krow + ((c*32 + quad*8) ^ swzr)) = v;
    }
    asm volatile("s_waitcnt lgkmcnt(0)" ::: "memory");
    qf0 = *(const s16x8*)(krow + ((quad*16)      ^ swzr));
    qf1 = *(const s16x8*)(krow + ((64 + quad*16) ^ swzr));
    asm volatile("s_waitcnt lgkmcnt(0)" ::: "memory");

    #pragma unroll
    for (int c = 0; c < 4; ++c){
      s16x4 v;
      #pragma unroll
      for (int i = 0; i < 4; ++i) v[i] = f2bf(ak[c][i]);
      *(s16x4*)(krow + ((c*32 + quad*8) ^ swzr)) = v;
    }
    #pragma unroll
    for (int c = 0; c < 4; ++c){
      const int h = c*16 + l15;
      s16x4 v;
      #pragma unroll
      for (int i = 0; i < 4; ++i) v[i] = f2bf(av[c][i]);
      *(s16x4*)(VtsB + h*512 + (((r0 + quad*4)*2) ^ ((h & 7) << 4))) = v;
    }
  };

  project(F0*16, qA0, qA1);
  project(F1*16, qB0, qB1);

  __syncthreads();

  float* ob = out + (long)b*256*64;
  short* Pw = Pp[w];
  const int swz = (l15 & 7) << 4;

  auto attend = [&](int F, s16x8 qf0, s16x8 qf1){
    const int qb = F*16;
    const int NF = F + 1;
    const int NS = (NF + 1) >> 1;

    f32x4 sc[16];
    #pragma unroll
    for (int f = 0; f < 16; ++f){
      f32x4 a;
      #pragma unroll
      for (int r = 0; r < 4; ++r) a[r] = 0.0f;
      if (f < NF){
        const char* kp = KsB + (f*16 + l15)*128;
        s16x8 k0v = *(const s16x8*)(kp + ((quad*16)      ^ swz));
        s16x8 k1v = *(const s16x8*)(kp + ((64 + quad*16) ^ swz));
        a = __builtin_amdgcn_mfma_f32_16x16x32_bf16(qf0, k0v, a, 0, 0, 0);
        a = __builtin_amdgcn_mfma_f32_16x16x32_bf16(qf1, k1v, a, 0, 0, 0);
      }
      sc[f] = a;
    }

    float mx[4], sm[4];
    #pragma unroll
    for (int r = 0; r < 4; ++r) mx[r] = -3.0e38f;
    #pragma unroll
    for (int f = 0; f < 16; ++f){
      if (f < NF){
        const int key = f*16 + l15;
        #pragma unroll
        for (int r = 0; r < 4; ++r){
          const int qg = qb + quad*4 + r;
          float s = sc[f][r] * 0.125f;
          s = (key <= qg) ? s : -1.0e30f;
          sc[f][r] = s;
          mx[r] = fmaxf(mx[r], s);
        }
      }
    }
    #pragma unroll
    for (int r = 0; r < 4; ++r){
      #pragma unroll
      for (int off = 1; off < 16; off <<= 1) mx[r] = fmaxf(mx[r], __shfl_xor(mx[r], off, 16));
    }
    #pragma unroll
    for (int r = 0; r < 4; ++r) sm[r] = 0.0f;
    #pragma unroll
    for (int f = 0; f < 16; ++f){
      if (f < NF){
        #pragma unroll
        for (int r = 0; r < 4; ++r){
          float p = exp2f((sc[f][r] - mx[r]) * 1.44269504f);
          sc[f][r] = p;
          sm[r] += p;
        }
      }
    }
    #pragma unroll
    for (int r = 0; r < 4; ++r){
      #pragma unroll
      for (int off = 1; off < 16; off <<= 1) sm[r] += __shfl_xor(sm[r], off, 16);
    }

    f32x4 o[4];
    #pragma unroll
    for (int h0 = 0; h0 < 4; ++h0)
      #pragma unroll
      for (int r = 0; r < 4; ++r) o[h0][r] = 0.0f;

    #pragma unroll
    for (int ks = 0; ks < 8; ++ks){
      if (ks < NS){
        #pragma unroll
        for (int fi = 0; fi < 2; ++fi){
          const int f = 2*ks + fi;
          #pragma unroll
          for (int r = 0; r < 4; ++r){
            short v = 0;
            if (f < NF) v = f2bf(sc[f][r]);
            Pw[(quad*4 + r)*40 + fi*16 + l15] = v;
          }
        }
        s16x8 pf = *(const s16x8*)(Pw + l15*40 + quad*8);
        #pragma unroll
        for (int h0 = 0; h0 < 4; ++h0){
          const char* vp = VtsB + (h0*16 + l15)*512;
          s16x8 vf = *(const s16x8*)(vp + ((ks*64 + quad*16) ^ swz));
          o[h0] = __builtin_amdgcn_mfma_f32_16x16x32_bf16(pf, vf, o[h0], 0, 0, 0);
        }
      }
    }

    #pragma unroll
    for (int r = 0; r < 4; ++r){
      const float inv = 1.0f / sm[r];
      #pragma unroll
      for (int h0 = 0; h0 < 4; ++h0)
        ob[(qb + quad*4 + r)*64 + h0*16 + l15] = o[h0][r] * inv;
    }
  };

  attend(F0, qA0, qA1);
  attend(F1, qB0, qB1);
}

extern "C" void kernel_launch(void* const* d_in, const int* in_sizes, int n_in,
                              void* d_out, int out_size, void* d_ws, size_t ws_size,
                              hipStream_t stream){
  const float* x  = (const float*)d_in[0];
  const float* Wq = (const float*)d_in[1];
  const float* Wk = (const float*)d_in[2];
  const float* Wv = (const float*)d_in[3];
  float* out = (float*)d_out;

  short* Wt = (short*)d_ws;                        // 192*384*2 = 147456 B
  const size_t need = 147456 + 3ull*16777216ull;   // Wt + Q/K/V bf16 images

  hipLaunchKernelGGL(wt_prep_kernel, dim3(288), dim3(256), 0, stream, Wq, Wk, Wv, Wt);
  if (ws_size >= need){
    short* Qg = (short*)((char*)d_ws + 147456);
    short* Kg = Qg + 8388608;
    short* Vg = Kg + 8388608;
    hipLaunchKernelGGL(qkv3_kernel, dim3(1024), dim3(512), 0, stream, x, Wt, Qg, Kg, Vg);
    hipLaunchKernelGGL(attn_kernel, dim3(512),  dim3(512), 0, stream, Qg, Kg, Vg, out);
  } else {
    hipLaunchKernelGGL(fused2_kernel, dim3(512), dim3(512), 0, stream, x, Wt, out);
  }
}